// Round 1
// baseline (653.632 us; speedup 1.0000x reference)
//
#include <hip/hip_runtime.h>

// Problem constants
#define DN 256   // D
#define N2C 512  // N2 (= E)
#define TC 4096  // T
#define EC 512   // E

// ---------------------------------------------------------------------------
// K1: new2[j,d] = sum_i x2[i,d]*W2[j,i,d] + sum_i R2[j,i,d] + x2[j,d]
// One block per j. 512 threads = 8 i-groups x 64 d4 (float4 over d).
// Streams 1 MB (W2 row + R2 row) per block; HBM-bound.
// ---------------------------------------------------------------------------
__global__ __launch_bounds__(512) void k1_new2(const float* __restrict__ emb,
                                               const float* __restrict__ W2,
                                               const float* __restrict__ R2,
                                               float* __restrict__ out) {
    const int d4  = threadIdx.x & 63;   // float4 index over d (64 x 4 = 256)
    const int grp = threadIdx.x >> 6;   // 0..7, i-partition
    const int j   = blockIdx.x;         // 0..511

    const float4* W = (const float4*)(W2 + (size_t)j * N2C * DN);
    const float4* R = (const float4*)(R2 + (size_t)j * N2C * DN);
    const float4* X = (const float4*)emb;  // x2 = emb[:512]

    float ax = 0.f, ay = 0.f, az = 0.f, aw = 0.f;
    const int i0 = grp * 64;
    #pragma unroll 4
    for (int i = i0; i < i0 + 64; ++i) {
        float4 w = W[i * 64 + d4];
        float4 r = R[i * 64 + d4];
        float4 x = X[i * 64 + d4];
        ax += x.x * w.x + r.x;
        ay += x.y * w.y + r.y;
        az += x.z * w.z + r.z;
        aw += x.w * w.w + r.w;
    }

    __shared__ float4 red[8][64];
    float4 mine; mine.x = ax; mine.y = ay; mine.z = az; mine.w = aw;
    red[grp][d4] = mine;
    __syncthreads();

    if (grp == 0) {
        float sx = 0.f, sy = 0.f, sz = 0.f, sw = 0.f;
        #pragma unroll
        for (int g = 0; g < 8; ++g) {
            float4 v = red[g][d4];
            sx += v.x; sy += v.y; sz += v.z; sw += v.w;
        }
        float4 x = X[j * 64 + d4];
        float4 o;
        o.x = sx + x.x; o.y = sy + x.y; o.z = sz + x.z; o.w = sw + x.w;
        ((float4*)out)[j * 64 + d4] = o;
    }
}

// ---------------------------------------------------------------------------
// K2a: S[d] = sum over rows 512..4607 of emb[row][d]  (column sum)
// Grid 64 blocks x 256 threads; each block sums 64 rows, then atomicAdd.
// S must be zeroed beforehand (hipMemsetAsync).
// ---------------------------------------------------------------------------
__global__ __launch_bounds__(256) void k2a_colsum(const float* __restrict__ emb,
                                                  float* __restrict__ S) {
    const int d = threadIdx.x;
    const float* base = emb + (size_t)N2C * DN;
    const int r0 = blockIdx.x * 64;
    float s = 0.f;
    #pragma unroll 4
    for (int r = r0; r < r0 + 64; ++r) s += base[(size_t)r * DN + d];
    atomicAdd(&S[d], s);
}

// ---------------------------------------------------------------------------
// K2b: deg1[row] = 1 + nnz(A1[row,:])  as float. Wave per row (4 rows/block).
// ---------------------------------------------------------------------------
__global__ __launch_bounds__(256) void k2b_deg1(const int* __restrict__ A1,
                                                float* __restrict__ deg1) {
    const int row  = blockIdx.x * 4 + (threadIdx.x >> 6);
    const int lane = threadIdx.x & 63;
    const int4* p = (const int4*)(A1 + (size_t)row * TC);
    int cnt = 0;
    #pragma unroll
    for (int k = 0; k < 16; ++k) {
        int4 v = p[k * 64 + lane];
        cnt += (v.x != 0) + (v.y != 0) + (v.z != 0) + (v.w != 0);
    }
    #pragma unroll
    for (int off = 32; off > 0; off >>= 1) cnt += __shfl_down(cnt, off, 64);
    if (lane == 0) deg1[row] = 1.0f + (float)cnt;
}

// ---------------------------------------------------------------------------
// K3: new_common[t,d] = (sub[t,d]+S[d])*(1 - S[d]/deg1[t])
//                     + sum_e A2f[e,t]*new2[e,d] + (512 - deg2[t])
// new2 = out rows 0..511 (written by K1). Writes out rows 512..4607.
// 4 t per block (64 d4-threads each); loop over e=0..511.
// ---------------------------------------------------------------------------
__global__ __launch_bounds__(256) void k3_common(const float* __restrict__ emb,
                                                 const int* __restrict__ A2,
                                                 const float* __restrict__ S,
                                                 const float* __restrict__ deg1,
                                                 float* out) {
    const int t  = blockIdx.x * 4 + (threadIdx.x >> 6);
    const int d4 = threadIdx.x & 63;
    const float4* spec = (const float4*)out;  // new2, rows 0..511

    float ax = 0.f, ay = 0.f, az = 0.f, aw = 0.f;
    int cnt = 0;
    #pragma unroll 4
    for (int e = 0; e < EC; ++e) {
        int a = A2[(size_t)e * TC + t];
        float m = (a != 0) ? 1.0f : 0.0f;
        cnt += (a != 0);
        float4 v = spec[e * 64 + d4];
        ax += m * v.x; ay += m * v.y; az += m * v.z; aw += m * v.w;
    }
    const float addc = (float)(EC - cnt);

    float4 Sv = ((const float4*)S)[d4];
    float  dg = deg1[t];
    float inv = 1.0f / dg;
    float4 sub = ((const float4*)emb)[(N2C + t) * 64 + d4];

    float4 o;
    o.x = (sub.x + Sv.x) * (1.0f - Sv.x * inv) + ax + addc;
    o.y = (sub.y + Sv.y) * (1.0f - Sv.y * inv) + ay + addc;
    o.z = (sub.z + Sv.z) * (1.0f - Sv.z * inv) + az + addc;
    o.w = (sub.w + Sv.w) * (1.0f - Sv.w * inv) + aw + addc;
    ((float4*)out)[(N2C + t) * 64 + d4] = o;
}

// ---------------------------------------------------------------------------
// K4: msg3[e,d] = sum_t A3f[t,e]*new_common[t,d] + (4096 - deg3[e])
//     new_spec[e,d] = new2[e,d] * (1 - msg3[e,d]/(1+deg3[e]))
// Reads and overwrites out rows 0..511 element-wise (no cross-thread hazard).
// 4 e per block; loop over t=0..4095 reading new_common (L2/L3-resident 4MB).
// ---------------------------------------------------------------------------
__global__ __launch_bounds__(256) void k4_spec(const int* __restrict__ A3,
                                               float* out) {
    const int e  = blockIdx.x * 4 + (threadIdx.x >> 6);
    const int d4 = threadIdx.x & 63;
    const float4* nc = (const float4*)(out + (size_t)N2C * DN);  // new_common

    float ax = 0.f, ay = 0.f, az = 0.f, aw = 0.f;
    int cnt = 0;
    #pragma unroll 4
    for (int t = 0; t < TC; ++t) {
        int a = A3[(size_t)t * EC + e];
        float m = (a != 0) ? 1.0f : 0.0f;
        cnt += (a != 0);
        float4 v = nc[t * 64 + d4];
        ax += m * v.x; ay += m * v.y; az += m * v.z; aw += m * v.w;
    }
    const float msg_add = (float)(TC - cnt);
    const float inv = 1.0f / (1.0f + (float)cnt);

    float4 cur = ((const float4*)out)[e * 64 + d4];
    float4 o;
    o.x = cur.x * (1.0f - (ax + msg_add) * inv);
    o.y = cur.y * (1.0f - (ay + msg_add) * inv);
    o.z = cur.z * (1.0f - (az + msg_add) * inv);
    o.w = cur.w * (1.0f - (aw + msg_add) * inv);
    ((float4*)out)[e * 64 + d4] = o;
}

extern "C" void kernel_launch(void* const* d_in, const int* in_sizes, int n_in,
                              void* d_out, int out_size, void* d_ws, size_t ws_size,
                              hipStream_t stream) {
    const float* emb = (const float*)d_in[0];
    const float* W2  = (const float*)d_in[1];
    const float* R2  = (const float*)d_in[2];
    const int*   A1  = (const int*)d_in[3];
    const int*   A2  = (const int*)d_in[4];
    const int*   A3  = (const int*)d_in[5];
    float* out = (float*)d_out;

    float* S    = (float*)d_ws;      // 256 floats
    float* deg1 = S + DN;            // 4096 floats

    hipMemsetAsync(d_ws, 0, DN * sizeof(float), stream);

    k1_new2<<<N2C, 512, 0, stream>>>(emb, W2, R2, out);
    k2a_colsum<<<TC / 64, 256, 0, stream>>>(emb, S);
    k2b_deg1<<<TC / 4, 256, 0, stream>>>(A1, deg1);
    k3_common<<<TC / 4, 256, 0, stream>>>(emb, A2, S, deg1, out);
    k4_spec<<<EC / 4, 256, 0, stream>>>(A3, out);
}

// Round 2
// 275.953 us; speedup vs baseline: 2.3686x; 2.3686x over previous
//
#include <hip/hip_runtime.h>
#include <stdint.h>

// Problem constants
#define DN 256   // D
#define N2C 512  // N2 (= E)
#define TC 4096  // T
#define EC 512   // E

// ---------------------------------------------------------------------------
// K1: new2[j,d] = sum_i x2[i,d]*W2[j,i,d] + sum_i R2[j,i,d] + x2[j,d]
// One block per j. 512 threads = 8 i-groups x 64 d4 (float4 over d).
// Streams 1 MB (W2 row + R2 row) per block; HBM-bound (~512 MB total).
// ---------------------------------------------------------------------------
__global__ __launch_bounds__(512) void k1_new2(const float* __restrict__ emb,
                                               const float* __restrict__ W2,
                                               const float* __restrict__ R2,
                                               float* __restrict__ out) {
    const int d4  = threadIdx.x & 63;
    const int grp = threadIdx.x >> 6;
    const int j   = blockIdx.x;

    const float4* W = (const float4*)(W2 + (size_t)j * N2C * DN);
    const float4* R = (const float4*)(R2 + (size_t)j * N2C * DN);
    const float4* X = (const float4*)emb;

    float ax = 0.f, ay = 0.f, az = 0.f, aw = 0.f;
    const int i0 = grp * 64;
    #pragma unroll 4
    for (int i = i0; i < i0 + 64; ++i) {
        float4 w = W[i * 64 + d4];
        float4 r = R[i * 64 + d4];
        float4 x = X[i * 64 + d4];
        ax += x.x * w.x + r.x;
        ay += x.y * w.y + r.y;
        az += x.z * w.z + r.z;
        aw += x.w * w.w + r.w;
    }

    __shared__ float4 red[8][64];
    float4 mine; mine.x = ax; mine.y = ay; mine.z = az; mine.w = aw;
    red[grp][d4] = mine;
    __syncthreads();

    if (grp == 0) {
        float sx = 0.f, sy = 0.f, sz = 0.f, sw = 0.f;
        #pragma unroll
        for (int g = 0; g < 8; ++g) {
            float4 v = red[g][d4];
            sx += v.x; sy += v.y; sz += v.z; sw += v.w;
        }
        float4 x = X[j * 64 + d4];
        float4 o;
        o.x = sx + x.x; o.y = sy + x.y; o.z = sz + x.z; o.w = sw + x.w;
        ((float4*)out)[j * 64 + d4] = o;
    }
}

// ---------------------------------------------------------------------------
// K2a: S[d] = column sum of emb rows 512..4607. atomicAdd into zeroed ws.
// ---------------------------------------------------------------------------
__global__ __launch_bounds__(256) void k2a_colsum(const float* __restrict__ emb,
                                                  float* __restrict__ S) {
    const int d = threadIdx.x;
    const float* base = emb + (size_t)N2C * DN;
    const int r0 = blockIdx.x * 64;
    float s = 0.f;
    #pragma unroll 4
    for (int r = r0; r < r0 + 64; ++r) s += base[(size_t)r * DN + d];
    atomicAdd(&S[d], s);
}

// ---------------------------------------------------------------------------
// K2b: deg1[row] = 1 + nnz(A1[row,:]). Wave per row.
// ---------------------------------------------------------------------------
__global__ __launch_bounds__(256) void k2b_deg1(const int* __restrict__ A1,
                                                float* __restrict__ deg1) {
    const int row  = blockIdx.x * 4 + (threadIdx.x >> 6);
    const int lane = threadIdx.x & 63;
    const int4* p = (const int4*)(A1 + (size_t)row * TC);
    int cnt = 0;
    #pragma unroll
    for (int k = 0; k < 16; ++k) {
        int4 v = p[k * 64 + lane];
        cnt += (v.x != 0) + (v.y != 0) + (v.z != 0) + (v.w != 0);
    }
    #pragma unroll
    for (int off = 32; off > 0; off >>= 1) cnt += __shfl_down(cnt, off, 64);
    if (lane == 0) deg1[row] = 1.0f + (float)cnt;
}

// ---------------------------------------------------------------------------
// P2: pack A2 (E x T, [e][t]) transposed into bitmasks:
//     PT2[t][w] bit b = (A2[w*32+b][t] != 0),  w in [0,16)
// Tile 64e x 64t via LDS; coalesced global reads.
// ---------------------------------------------------------------------------
__global__ __launch_bounds__(256) void p2_pack(const int* __restrict__ A2,
                                               uint32_t* __restrict__ PT2) {
    __shared__ uint32_t lds[64][65];
    const int e0 = (blockIdx.x & 7) * 64;
    const int t0 = (blockIdx.x >> 3) * 64;
    const int tx = threadIdx.x & 63;
    const int ty = threadIdx.x >> 6;
    #pragma unroll
    for (int k = 0; k < 16; ++k) {
        int el = ty * 16 + k;
        lds[el][tx] = (A2[(size_t)(e0 + el) * TC + t0 + tx] != 0) ? 1u : 0u;
    }
    __syncthreads();
    if (threadIdx.x < 128) {
        const int tl = threadIdx.x & 63;
        const int w  = threadIdx.x >> 6;  // 0 or 1
        uint32_t bits = 0;
        #pragma unroll
        for (int b = 0; b < 32; ++b) bits |= lds[w * 32 + b][tl] << b;
        PT2[(size_t)(t0 + tl) * 16 + (e0 >> 5) + w] = bits;
    }
}

// ---------------------------------------------------------------------------
// P3: pack A3 (T x E, [t][e]) transposed into bitmasks:
//     PT3[e][w] bit b = (A3[w*32+b][e] != 0),  w in [0,128)
// ---------------------------------------------------------------------------
__global__ __launch_bounds__(256) void p3_pack(const int* __restrict__ A3,
                                               uint32_t* __restrict__ PT3) {
    __shared__ uint32_t lds[64][65];
    const int t0 = (blockIdx.x >> 3) * 64;
    const int e0 = (blockIdx.x & 7) * 64;
    const int ex = threadIdx.x & 63;
    const int ty = threadIdx.x >> 6;
    #pragma unroll
    for (int k = 0; k < 16; ++k) {
        int tl = ty * 16 + k;
        lds[tl][ex] = (A3[(size_t)(t0 + tl) * EC + e0 + ex] != 0) ? 1u : 0u;
    }
    __syncthreads();
    if (threadIdx.x < 128) {
        const int el = threadIdx.x & 63;
        const int w  = threadIdx.x >> 6;  // 0 or 1
        uint32_t bits = 0;
        #pragma unroll
        for (int b = 0; b < 32; ++b) bits |= lds[w * 32 + b][el] << b;
        PT3[(size_t)(e0 + el) * 128 + (t0 >> 5) + w] = bits;
    }
}

// ---------------------------------------------------------------------------
// K3: new_common[t,d] = (sub[t,d]+S[d])*(1 - S[d]/deg1[t])
//                     + sum_e A2f[e,t]*new2[e,d] + (512 - deg2[t])
// 4 t per block; bitmask-driven sparse accumulation over e (wave-uniform).
// ---------------------------------------------------------------------------
__global__ __launch_bounds__(256) void k3_common(const float* __restrict__ emb,
                                                 const uint32_t* __restrict__ PT2,
                                                 const float* __restrict__ S,
                                                 const float* __restrict__ deg1,
                                                 float* out) {
    const int t  = blockIdx.x * 4 + (threadIdx.x >> 6);
    const int d4 = threadIdx.x & 63;
    const float4* spec = (const float4*)out;  // new2, rows 0..511
    const uint32_t* pw = PT2 + (size_t)t * 16;

    float ax = 0.f, ay = 0.f, az = 0.f, aw = 0.f;
    int cnt = 0;
    #pragma unroll
    for (int w = 0; w < 16; ++w) {
        uint32_t mask = pw[w];
        cnt += __popc(mask);
        while (mask) {
            int b = __ffs(mask) - 1;
            mask &= mask - 1;
            float4 v = spec[(w * 32 + b) * 64 + d4];
            ax += v.x; ay += v.y; az += v.z; aw += v.w;
        }
    }
    const float addc = (float)(EC - cnt);

    float4 Sv = ((const float4*)S)[d4];
    float inv = 1.0f / deg1[t];
    float4 sub = ((const float4*)emb)[(N2C + t) * 64 + d4];

    float4 o;
    o.x = (sub.x + Sv.x) * (1.0f - Sv.x * inv) + ax + addc;
    o.y = (sub.y + Sv.y) * (1.0f - Sv.y * inv) + ay + addc;
    o.z = (sub.z + Sv.z) * (1.0f - Sv.z * inv) + az + addc;
    o.w = (sub.w + Sv.w) * (1.0f - Sv.w * inv) + aw + addc;
    ((float4*)out)[(N2C + t) * 64 + d4] = o;
}

// ---------------------------------------------------------------------------
// K4: msg3[e,d] = sum_t A3f[t,e]*new_common[t,d] + (4096 - deg3[e])
//     new_spec[e,d] = new2[e,d] * (1 - msg3[e,d]/(1+deg3[e]))
// One block per e: 4 t-chunk groups x 64 d4; bitmask-driven; LDS reduce.
// ---------------------------------------------------------------------------
__global__ __launch_bounds__(256) void k4_spec(const uint32_t* __restrict__ PT3,
                                               float* out) {
    const int e    = blockIdx.x;
    const int d4   = threadIdx.x & 63;
    const int chnk = threadIdx.x >> 6;  // 0..3, each covers 1024 t (32 words)
    const float4* nc = (const float4*)(out + (size_t)N2C * DN);
    const uint32_t* pw = PT3 + (size_t)e * 128 + chnk * 32;

    float ax = 0.f, ay = 0.f, az = 0.f, aw = 0.f;
    int cnt = 0;
    #pragma unroll 4
    for (int w = 0; w < 32; ++w) {
        uint32_t mask = pw[w];
        cnt += __popc(mask);
        const int tbase = (chnk * 32 + w) * 32;
        while (mask) {
            int b = __ffs(mask) - 1;
            mask &= mask - 1;
            float4 v = nc[(size_t)(tbase + b) * 64 + d4];
            ax += v.x; ay += v.y; az += v.z; aw += v.w;
        }
    }

    __shared__ float4 red[4][64];
    __shared__ int cnts[4];
    float4 mine; mine.x = ax; mine.y = ay; mine.z = az; mine.w = aw;
    red[chnk][d4] = mine;
    if (d4 == 0) cnts[chnk] = cnt;
    __syncthreads();

    if (chnk == 0) {
        float sx = 0.f, sy = 0.f, sz = 0.f, sw = 0.f;
        #pragma unroll
        for (int g = 0; g < 4; ++g) {
            float4 v = red[g][d4];
            sx += v.x; sy += v.y; sz += v.z; sw += v.w;
        }
        int deg3 = cnts[0] + cnts[1] + cnts[2] + cnts[3];
        const float msg_add = (float)(TC - deg3);
        const float inv = 1.0f / (1.0f + (float)deg3);
        float4 cur = ((const float4*)out)[e * 64 + d4];
        float4 o;
        o.x = cur.x * (1.0f - (sx + msg_add) * inv);
        o.y = cur.y * (1.0f - (sy + msg_add) * inv);
        o.z = cur.z * (1.0f - (sz + msg_add) * inv);
        o.w = cur.w * (1.0f - (sw + msg_add) * inv);
        ((float4*)out)[e * 64 + d4] = o;
    }
}

extern "C" void kernel_launch(void* const* d_in, const int* in_sizes, int n_in,
                              void* d_out, int out_size, void* d_ws, size_t ws_size,
                              hipStream_t stream) {
    const float* emb = (const float*)d_in[0];
    const float* W2  = (const float*)d_in[1];
    const float* R2  = (const float*)d_in[2];
    const int*   A1  = (const int*)d_in[3];
    const int*   A2  = (const int*)d_in[4];
    const int*   A3  = (const int*)d_in[5];
    float* out = (float*)d_out;

    float*    S    = (float*)d_ws;                    // 256 floats
    float*    deg1 = S + DN;                          // 4096 floats
    uint32_t* PT2  = (uint32_t*)(deg1 + TC);          // 4096*16 words (256 KB)
    uint32_t* PT3  = PT2 + (size_t)TC * 16;           // 512*128 words (256 KB)

    hipMemsetAsync(d_ws, 0, DN * sizeof(float), stream);

    p2_pack<<<512, 256, 0, stream>>>(A2, PT2);
    p3_pack<<<512, 256, 0, stream>>>(A3, PT3);
    k2a_colsum<<<TC / 64, 256, 0, stream>>>(emb, S);
    k2b_deg1<<<TC / 4, 256, 0, stream>>>(A1, deg1);
    k1_new2<<<N2C, 512, 0, stream>>>(emb, W2, R2, out);
    k3_common<<<TC / 4, 256, 0, stream>>>(emb, PT2, S, deg1, out);
    k4_spec<<<EC, 256, 0, stream>>>(PT3, out);
}

// Round 3
// 213.532 us; speedup vs baseline: 3.0610x; 1.2923x over previous
//
#include <hip/hip_runtime.h>
#include <stdint.h>

// Problem constants
#define DN 256   // D
#define N2C 512  // N2 (= E)
#define TC 4096  // T
#define EC 512   // E

// Fused-prep block ranges (all 512-thread blocks)
#define B_K1_END  512    // k1: one block per j
#define B_K2A_END 576    // colsum: 64 blocks x 64 rows
#define B_K2B_END 1088   // deg1: 512 blocks x 8 rows
#define B_P2_END  1600   // pack A2^T: 512 tiles
#define B_P3_END  2112   // pack A3^T: 512 tiles

// ---------------------------------------------------------------------------
// prep_fused: block-range-partitioned union of 5 independent jobs so the
// A1/A2/A3 streams overlap the dominant W2/R2 stream (~596 MB total HBM).
//  k1 : new2[j,d] = sum_i x2[i,d]*W2[j,i,d] + sum_i R2[j,i,d] + x2[j,d]
//  k2a: S[d] = colsum of emb rows 512..4607 (atomicAdd into zeroed S)
//  k2b: deg1[row] = 1 + nnz(A1[row,:])
//  p2 : PT2[t][w] bit b = (A2[w*32+b][t] != 0), w in [0,16)
//  p3 : PT3[e][w] bit b = (A3[w*32+b][e] != 0), w in [0,128)
// ---------------------------------------------------------------------------
__global__ __launch_bounds__(512) void prep_fused(
    const float* __restrict__ emb, const float* __restrict__ W2,
    const float* __restrict__ R2, const int* __restrict__ A1,
    const int* __restrict__ A2, const int* __restrict__ A3,
    float* __restrict__ out, float* __restrict__ S,
    float* __restrict__ deg1, uint32_t* __restrict__ PT2,
    uint32_t* __restrict__ PT3)
{
    __shared__ uint32_t ldsb[64][65];
    __shared__ float4 red[8][64];
    const int bid = blockIdx.x;
    const int tid = threadIdx.x;

    if (bid < B_K1_END) {
        // ---- k1 ----
        const int d4  = tid & 63;
        const int grp = tid >> 6;
        const int j   = bid;
        const float4* W = (const float4*)(W2 + (size_t)j * N2C * DN);
        const float4* R = (const float4*)(R2 + (size_t)j * N2C * DN);
        const float4* X = (const float4*)emb;

        float ax = 0.f, ay = 0.f, az = 0.f, aw = 0.f;
        const int i0 = grp * 64;
        #pragma unroll 4
        for (int i = i0; i < i0 + 64; ++i) {
            float4 w = W[i * 64 + d4];
            float4 r = R[i * 64 + d4];
            float4 x = X[i * 64 + d4];
            ax += x.x * w.x + r.x;
            ay += x.y * w.y + r.y;
            az += x.z * w.z + r.z;
            aw += x.w * w.w + r.w;
        }
        float4 mine; mine.x = ax; mine.y = ay; mine.z = az; mine.w = aw;
        red[grp][d4] = mine;
        __syncthreads();
        if (grp == 0) {
            float sx = 0.f, sy = 0.f, sz = 0.f, sw = 0.f;
            #pragma unroll
            for (int g = 0; g < 8; ++g) {
                float4 v = red[g][d4];
                sx += v.x; sy += v.y; sz += v.z; sw += v.w;
            }
            float4 x = X[j * 64 + d4];
            float4 o;
            o.x = sx + x.x; o.y = sy + x.y; o.z = sz + x.z; o.w = sw + x.w;
            ((float4*)out)[j * 64 + d4] = o;
        }
    } else if (bid < B_K2A_END) {
        // ---- k2a ----
        const int b = bid - B_K1_END;
        const int d = tid & 255;
        const int h = tid >> 8;  // 0 or 1
        const float* base = emb + (size_t)N2C * DN;
        const int r0 = b * 64 + h * 32;
        float s = 0.f;
        #pragma unroll 4
        for (int r = r0; r < r0 + 32; ++r) s += base[(size_t)r * DN + d];
        atomicAdd(&S[d], s);
    } else if (bid < B_K2B_END) {
        // ---- k2b ----
        const int b    = bid - B_K2A_END;
        const int row  = b * 8 + (tid >> 6);
        const int lane = tid & 63;
        const int4* p = (const int4*)(A1 + (size_t)row * TC);
        int cnt = 0;
        #pragma unroll
        for (int k = 0; k < 16; ++k) {
            int4 v = p[k * 64 + lane];
            cnt += (v.x != 0) + (v.y != 0) + (v.z != 0) + (v.w != 0);
        }
        #pragma unroll
        for (int off = 32; off > 0; off >>= 1) cnt += __shfl_down(cnt, off, 64);
        if (lane == 0) deg1[row] = 1.0f + (float)cnt;
    } else if (bid < B_P2_END) {
        // ---- p2 ----
        const int bb = bid - B_K2B_END;
        const int e0 = (bb & 7) * 64;
        const int t0 = (bb >> 3) * 64;
        const int tx = tid & 63;
        const int ty = tid >> 6;  // 0..7
        #pragma unroll
        for (int k = 0; k < 8; ++k) {
            int el = ty * 8 + k;
            ldsb[el][tx] = (A2[(size_t)(e0 + el) * TC + t0 + tx] != 0) ? 1u : 0u;
        }
        __syncthreads();
        if (tid < 128) {
            const int tl = tid & 63;
            const int w  = tid >> 6;
            uint32_t bits = 0;
            #pragma unroll
            for (int b = 0; b < 32; ++b) bits |= ldsb[w * 32 + b][tl] << b;
            PT2[(size_t)(t0 + tl) * 16 + (e0 >> 5) + w] = bits;
        }
    } else {
        // ---- p3 ----
        const int bb = bid - B_P2_END;
        const int t0 = (bb >> 3) * 64;
        const int e0 = (bb & 7) * 64;
        const int ex = tid & 63;
        const int ty = tid >> 6;  // 0..7
        #pragma unroll
        for (int k = 0; k < 8; ++k) {
            int tl = ty * 8 + k;
            ldsb[tl][ex] = (A3[(size_t)(t0 + tl) * EC + e0 + ex] != 0) ? 1u : 0u;
        }
        __syncthreads();
        if (tid < 128) {
            const int el = tid & 63;
            const int w  = tid >> 6;
            uint32_t bits = 0;
            #pragma unroll
            for (int b = 0; b < 32; ++b) bits |= ldsb[w * 32 + b][el] << b;
            PT3[(size_t)(e0 + el) * 128 + (t0 >> 5) + w] = bits;
        }
    }
}

// ---------------------------------------------------------------------------
// k3_dense: new_common[t,d] = (sub+S)*(1 - S/deg1) + A2f^T@new2 + (512-deg2)
// Dense bit-FMA: block = 16 t x 256 d (256 thr), thread owns 4 t x 1 float4.
// Per e: one coalesced 1 KB spec-row load serves 16 FMAs. VALU-bound.
// ---------------------------------------------------------------------------
__global__ __launch_bounds__(256) void k3_dense(
    const float* __restrict__ emb, const uint32_t* __restrict__ PT2,
    const float* __restrict__ S, const float* __restrict__ deg1,
    float* out)
{
    const int d4 = threadIdx.x & 63;
    const int tg = threadIdx.x >> 6;
    const int t0 = blockIdx.x * 16 + tg * 4;
    const float4* spec = (const float4*)out;  // new2, rows 0..511
    const uint32_t* pt = PT2 + (size_t)t0 * 16;

    float4 a0 = {0,0,0,0}, a1 = {0,0,0,0}, a2 = {0,0,0,0}, a3 = {0,0,0,0};
    int c0 = 0, c1 = 0, c2 = 0, c3 = 0;

    for (int ec = 0; ec < 16; ++ec) {
        const uint32_t w0 = pt[ec];
        const uint32_t w1 = pt[16 + ec];
        const uint32_t w2 = pt[32 + ec];
        const uint32_t w3 = pt[48 + ec];
        c0 += __popc(w0); c1 += __popc(w1); c2 += __popc(w2); c3 += __popc(w3);
        const float4* sp = spec + (size_t)ec * 32 * 64 + d4;
        #pragma unroll
        for (int b = 0; b < 32; ++b) {
            float4 v = sp[b * 64];
            float m0 = (float)((w0 >> b) & 1u);
            float m1 = (float)((w1 >> b) & 1u);
            float m2 = (float)((w2 >> b) & 1u);
            float m3 = (float)((w3 >> b) & 1u);
            a0.x = fmaf(m0, v.x, a0.x); a0.y = fmaf(m0, v.y, a0.y);
            a0.z = fmaf(m0, v.z, a0.z); a0.w = fmaf(m0, v.w, a0.w);
            a1.x = fmaf(m1, v.x, a1.x); a1.y = fmaf(m1, v.y, a1.y);
            a1.z = fmaf(m1, v.z, a1.z); a1.w = fmaf(m1, v.w, a1.w);
            a2.x = fmaf(m2, v.x, a2.x); a2.y = fmaf(m2, v.y, a2.y);
            a2.z = fmaf(m2, v.z, a2.z); a2.w = fmaf(m2, v.w, a2.w);
            a3.x = fmaf(m3, v.x, a3.x); a3.y = fmaf(m3, v.y, a3.y);
            a3.z = fmaf(m3, v.z, a3.z); a3.w = fmaf(m3, v.w, a3.w);
        }
    }

    const float4 Sv = ((const float4*)S)[d4];
#define K3_EPI(ak, ck, kk) { \
    const int t = t0 + kk; \
    const float inv = 1.0f / deg1[t]; \
    const float addc = (float)(EC - ck); \
    const float4 sub = ((const float4*)emb)[(size_t)(N2C + t) * 64 + d4]; \
    float4 o; \
    o.x = (sub.x + Sv.x) * (1.0f - Sv.x * inv) + ak.x + addc; \
    o.y = (sub.y + Sv.y) * (1.0f - Sv.y * inv) + ak.y + addc; \
    o.z = (sub.z + Sv.z) * (1.0f - Sv.z * inv) + ak.z + addc; \
    o.w = (sub.w + Sv.w) * (1.0f - Sv.w * inv) + ak.w + addc; \
    ((float4*)out)[(size_t)(N2C + t) * 64 + d4] = o; }
    K3_EPI(a0, c0, 0)
    K3_EPI(a1, c1, 1)
    K3_EPI(a2, c2, 2)
    K3_EPI(a3, c3, 3)
#undef K3_EPI
}

// ---------------------------------------------------------------------------
// k4_part: partial msg3 sums. Grid = 64 e-tiles x 4 t-chunks (1024 t each).
// Block = 256 thr: 64 d4 x 4 e-pairs (thread owns 2 e). Dense bit-FMA.
// P[chunk][e][d] = sum over chunk's t of bit3(t,e)*nc[t][d].
// ---------------------------------------------------------------------------
__global__ __launch_bounds__(256) void k4_part(
    const uint32_t* __restrict__ PT3, const float* __restrict__ out,
    float* __restrict__ P)
{
    const int d4    = threadIdx.x & 63;
    const int es    = threadIdx.x >> 6;   // 0..3
    const int etile = blockIdx.x >> 2;    // 0..63
    const int chunk = blockIdx.x & 3;     // 0..3
    const int e0 = etile * 8 + es * 2;    // thread owns e0, e0+1
    const float4* nc = (const float4*)(out + (size_t)N2C * DN);
    const uint32_t* p0 = PT3 + (size_t)e0 * 128 + chunk * 32;
    const uint32_t* p1 = p0 + 128;

    float4 a0 = {0,0,0,0}, a1 = {0,0,0,0};
    for (int w = 0; w < 32; ++w) {
        const uint32_t m0 = p0[w];
        const uint32_t m1 = p1[w];
        const float4* np = nc + (size_t)((chunk * 32 + w) * 32) * 64 + d4;
        #pragma unroll
        for (int b = 0; b < 32; ++b) {
            float4 v = np[b * 64];
            float f0 = (float)((m0 >> b) & 1u);
            float f1 = (float)((m1 >> b) & 1u);
            a0.x = fmaf(f0, v.x, a0.x); a0.y = fmaf(f0, v.y, a0.y);
            a0.z = fmaf(f0, v.z, a0.z); a0.w = fmaf(f0, v.w, a0.w);
            a1.x = fmaf(f1, v.x, a1.x); a1.y = fmaf(f1, v.y, a1.y);
            a1.z = fmaf(f1, v.z, a1.z); a1.w = fmaf(f1, v.w, a1.w);
        }
    }
    float4* Pp = (float4*)P;
    Pp[((size_t)chunk * EC + e0) * 64 + d4]     = a0;
    Pp[((size_t)chunk * EC + e0 + 1) * 64 + d4] = a1;
}

// ---------------------------------------------------------------------------
// k4_fin: combine 4 partials, compute deg3 by popcounting PT3[e][*],
// new_spec[e,d] = new2[e,d]*(1 - (msg3+4096-deg3)/(1+deg3)). Wave per e.
// ---------------------------------------------------------------------------
__global__ __launch_bounds__(256) void k4_fin(
    const uint32_t* __restrict__ PT3, const float* __restrict__ P,
    float* out)
{
    const int d4 = threadIdx.x & 63;
    const int es = threadIdx.x >> 6;
    const int e  = blockIdx.x * 4 + es;
    const float4* Pp = (const float4*)P;

    float4 s0 = Pp[((size_t)0 * EC + e) * 64 + d4];
    float4 s1 = Pp[((size_t)1 * EC + e) * 64 + d4];
    float4 s2 = Pp[((size_t)2 * EC + e) * 64 + d4];
    float4 s3 = Pp[((size_t)3 * EC + e) * 64 + d4];
    float4 s;
    s.x = s0.x + s1.x + s2.x + s3.x;
    s.y = s0.y + s1.y + s2.y + s3.y;
    s.z = s0.z + s1.z + s2.z + s3.z;
    s.w = s0.w + s1.w + s2.w + s3.w;

    int c = __popc(PT3[(size_t)e * 128 + 2 * d4]) +
            __popc(PT3[(size_t)e * 128 + 2 * d4 + 1]);
    #pragma unroll
    for (int off = 32; off > 0; off >>= 1) c += __shfl_xor(c, off, 64);

    const float msg_add = (float)(TC - c);
    const float inv = 1.0f / (1.0f + (float)c);
    float4 cur = ((const float4*)out)[(size_t)e * 64 + d4];
    float4 o;
    o.x = cur.x * (1.0f - (s.x + msg_add) * inv);
    o.y = cur.y * (1.0f - (s.y + msg_add) * inv);
    o.z = cur.z * (1.0f - (s.z + msg_add) * inv);
    o.w = cur.w * (1.0f - (s.w + msg_add) * inv);
    ((float4*)out)[(size_t)e * 64 + d4] = o;
}

extern "C" void kernel_launch(void* const* d_in, const int* in_sizes, int n_in,
                              void* d_out, int out_size, void* d_ws, size_t ws_size,
                              hipStream_t stream) {
    const float* emb = (const float*)d_in[0];
    const float* W2  = (const float*)d_in[1];
    const float* R2  = (const float*)d_in[2];
    const int*   A1  = (const int*)d_in[3];
    const int*   A2  = (const int*)d_in[4];
    const int*   A3  = (const int*)d_in[5];
    float* out = (float*)d_out;

    float*    S    = (float*)d_ws;                    // 256 floats
    float*    deg1 = S + DN;                          // 4096 floats
    uint32_t* PT2  = (uint32_t*)(deg1 + TC);          // 4096*16 words (256 KB)
    uint32_t* PT3  = PT2 + (size_t)TC * 16;           // 512*128 words (256 KB)
    float*    P    = (float*)(PT3 + (size_t)EC * 128);// 4*512*256 floats (2 MB)

    hipMemsetAsync(d_ws, 0, DN * sizeof(float), stream);

    prep_fused<<<B_P3_END, 512, 0, stream>>>(emb, W2, R2, A1, A2, A3,
                                             out, S, deg1, PT2, PT3);
    k3_dense<<<TC / 16, 256, 0, stream>>>(emb, PT2, S, deg1, out);
    k4_part<<<256, 256, 0, stream>>>(PT3, out, P);
    k4_fin<<<EC / 4, 256, 0, stream>>>(PT3, P, out);
}